// Round 1
// baseline (106.694 us; speedup 1.0000x reference)
//
#include <hip/hip_runtime.h>
#include <hip/hip_bf16.h>

typedef __attribute__((ext_vector_type(8))) short short8;
typedef __attribute__((ext_vector_type(4))) float f32x4;

#define MFMA16(a,b,c) __builtin_amdgcn_mfma_f32_16x16x32_bf16(a,b,c,0,0,0)

__device__ __forceinline__ ushort f2bf(float f) {
  union { float f; unsigned u; } v; v.f = f;
  unsigned u = v.u;
  return (ushort)((u + 0x7fffu + ((u >> 16) & 1u)) >> 16);
}

// ---------------------------------------------------------------------------
// Prep: W1 (2048x128 f32) -> W1t[n][k] bf16 (128x2048); Wq/Wk/Wv (128x128) ->
// transposed bf16, concatenated.
// ---------------------------------------------------------------------------
__global__ __launch_bounds__(256) void k_prep(const float* __restrict__ W1,
                                              const float* __restrict__ Wq,
                                              const float* __restrict__ Wk,
                                              const float* __restrict__ Wv,
                                              ushort* __restrict__ W1t,
                                              ushort* __restrict__ Wqkvt) {
  int idx = blockIdx.x * 256 + threadIdx.x;
  if (idx < 2048 * 128) {
    int n = idx >> 11, k = idx & 2047;          // W1t[n][k] = W1[k][n]
    W1t[idx] = f2bf(W1[(size_t)k * 128 + n]);
  } else {
    int r = idx - 2048 * 128;
    if (r < 3 * 16384) {
      int m = r >> 14, e = r & 16383;
      int n = e >> 7, k = e & 127;
      const float* W = (m == 0) ? Wq : (m == 1) ? Wk : Wv;
      Wqkvt[r] = f2bf(W[k * 128 + n]);
    }
  }
}

// ---------------------------------------------------------------------------
// GEMM1: h = relu((x + posenc) @ W1 + b1), bf16 MFMA, out bf16.
// BM=32, BN=128, BK=64. grid = 8192/32 = 256 blocks, 256 threads (4 waves).
// ---------------------------------------------------------------------------
__global__ __launch_bounds__(256) void k_gemm1(const float* __restrict__ x,
                                               const ushort* __restrict__ W1t,
                                               const float* __restrict__ b1,
                                               ushort* __restrict__ h_bf) {
  __shared__ short Al[32][72];    // +8 pad
  __shared__ short Bl[128][72];
  const int tid = threadIdx.x;
  const int lane = tid & 63, wv = tid >> 6;
  const int i0 = blockIdx.x * 32;
  const int arow = tid >> 3, akc = (tid & 7) * 8;   // A: 32 rows x 64 k
  const int brow = tid >> 1, bk0 = (tid & 1) * 32;  // B: 128 n-rows x 64 k
  const int grow = i0 + arow;
  const float sf = (float)(grow & 2047);            // seq position
  const int fr = lane & 15, kg = (lane >> 4) * 8;
  f32x4 acc[2][2] = {};
  for (int kt = 0; kt < 2048; kt += 64) {
    // stage A = x + posenc, cast bf16
    {
      const float* xp = x + (size_t)grow * 2048 + kt + akc;
      float4 f0 = *(const float4*)xp;
      float4 f1 = *(const float4*)(xp + 4);
      float vals[8] = {f0.x, f0.y, f0.z, f0.w, f1.x, f1.y, f1.z, f1.w};
      short8 av;
#pragma unroll
      for (int e = 0; e < 8; ++e) {
        int k = kt + akc + e;
        // inv_freq = 10000^(-(k>>1)/64); rev = s*inv_freq/(2pi)
        float c = exp2f((float)(k >> 1) * -0.2076205059304595f) * 0.15915494309189535f;
        float p = sf * c;
        float r = __builtin_fmaf(sf, c, -rintf(p));   // exact fract via fma
        float pe = (k & 1) ? __builtin_amdgcn_cosf(r) : __builtin_amdgcn_sinf(r);
        av[e] = (short)f2bf(vals[e] + pe);
      }
      *(short8*)&Al[arow][akc] = av;
    }
    // stage B from W1t (already bf16, n-major)
    {
      const ushort* wp = W1t + (size_t)brow * 2048 + kt + bk0;
#pragma unroll
      for (int e = 0; e < 4; ++e)
        *(short8*)&Bl[brow][bk0 + e * 8] = *(const short8*)(wp + e * 8);
    }
    __syncthreads();
#pragma unroll
    for (int kk = 0; kk < 2; ++kk) {
      short8 a0  = *(const short8*)&Al[fr][kk * 32 + kg];
      short8 a1  = *(const short8*)&Al[16 + fr][kk * 32 + kg];
      short8 b0  = *(const short8*)&Bl[wv * 32 + fr][kk * 32 + kg];
      short8 b1v = *(const short8*)&Bl[wv * 32 + 16 + fr][kk * 32 + kg];
      acc[0][0] = MFMA16(a0, b0,  acc[0][0]);
      acc[0][1] = MFMA16(a0, b1v, acc[0][1]);
      acc[1][0] = MFMA16(a1, b0,  acc[1][0]);
      acc[1][1] = MFMA16(a1, b1v, acc[1][1]);
    }
    __syncthreads();
  }
#pragma unroll
  for (int m = 0; m < 2; ++m)
#pragma unroll
    for (int n2 = 0; n2 < 2; ++n2) {
      int col = wv * 32 + n2 * 16 + fr;
      float bv = b1[col];
#pragma unroll
      for (int r = 0; r < 4; ++r) {
        int row = i0 + m * 16 + (lane >> 4) * 4 + r;
        float v = acc[m][n2][r] + bv;
        v = v > 0.f ? v : 0.f;
        h_bf[(size_t)row * 128 + col] = f2bf(v);
      }
    }
}

// ---------------------------------------------------------------------------
// QKV: {Q,K,V} = h_bf @ {Wq,Wk,Wv}, fp32 out. grid (256, 3).
// ---------------------------------------------------------------------------
__global__ __launch_bounds__(256) void k_qkv(const ushort* __restrict__ h_bf,
                                             const ushort* __restrict__ Wtb,
                                             float* __restrict__ outb) {
  __shared__ short Al[32][136];
  __shared__ short Bl[128][136];
  const int tid = threadIdx.x;
  const int lane = tid & 63, wv = tid >> 6;
  const int i0 = blockIdx.x * 32;
  const ushort* Wt = Wtb + (size_t)blockIdx.y * 16384;
  float* out = outb + (size_t)blockIdx.y * 1048576;
  {
    int row = tid >> 3, c = (tid & 7) * 16;
    const ushort* hp = h_bf + (size_t)(i0 + row) * 128 + c;
    *(short8*)&Al[row][c]     = *(const short8*)hp;
    *(short8*)&Al[row][c + 8] = *(const short8*)(hp + 8);
  }
  {
    int n = tid >> 1, h = (tid & 1) * 64;
    const ushort* wp = Wt + (size_t)n * 128 + h;
#pragma unroll
    for (int e = 0; e < 8; ++e)
      *(short8*)&Bl[n][h + e * 8] = *(const short8*)(wp + e * 8);
  }
  __syncthreads();
  const int fr = lane & 15, kg = (lane >> 4) * 8;
  f32x4 acc[2][2] = {};
#pragma unroll
  for (int kk = 0; kk < 4; ++kk) {
    short8 a0  = *(const short8*)&Al[fr][kk * 32 + kg];
    short8 a1  = *(const short8*)&Al[16 + fr][kk * 32 + kg];
    short8 b0  = *(const short8*)&Bl[wv * 32 + fr][kk * 32 + kg];
    short8 b1v = *(const short8*)&Bl[wv * 32 + 16 + fr][kk * 32 + kg];
    acc[0][0] = MFMA16(a0, b0,  acc[0][0]);
    acc[0][1] = MFMA16(a0, b1v, acc[0][1]);
    acc[1][0] = MFMA16(a1, b0,  acc[1][0]);
    acc[1][1] = MFMA16(a1, b1v, acc[1][1]);
  }
#pragma unroll
  for (int m = 0; m < 2; ++m)
#pragma unroll
    for (int n2 = 0; n2 < 2; ++n2)
#pragma unroll
      for (int r = 0; r < 4; ++r) {
        int row = i0 + m * 16 + (lane >> 4) * 4 + r;
        int col = wv * 32 + n2 * 16 + fr;
        out[(size_t)row * 128 + col] = acc[m][n2][r];
      }
}

// ---------------------------------------------------------------------------
// Attention: banded scores (window +-32, zero-padded => score 0 not -inf),
// softmax, PV, out-projection. Block = 32 rows of one batch. grid 256.
// ---------------------------------------------------------------------------
__global__ __launch_bounds__(256) void k_attn(const float* __restrict__ Qm,
                                              const float* __restrict__ Km,
                                              const float* __restrict__ Vm,
                                              const float* __restrict__ Wo,
                                              const float* __restrict__ bo,
                                              float* __restrict__ outp,
                                              float* __restrict__ attw) {
  __shared__ float Klds[96][132];
  __shared__ float Vlds[96][132];
  __shared__ float Qlds[32][132];
  __shared__ float sc[32][66];
  const int tid = threadIdx.x;
  const int lane = tid & 63, wv = tid >> 6;
  const int bx = blockIdx.x;
  const int b = bx >> 6;
  const int i0g = (bx & 63) << 5;
  const int rowbase = b * 2048 + i0g;
  // stage K,V rows j = i0g-32 .. i0g+63 (zeros outside [0,2048))
  for (int idx = tid; idx < 96 * 32; idx += 256) {
    int lr = idx >> 5, c4 = (idx & 31) * 4;
    int j = i0g - 32 + lr;
    float4 kv = {0.f, 0.f, 0.f, 0.f}, vv = {0.f, 0.f, 0.f, 0.f};
    if (j >= 0 && j < 2048) {
      size_t g = (size_t)(b * 2048 + j) * 128 + c4;
      kv = *(const float4*)(Km + g);
      vv = *(const float4*)(Vm + g);
    }
    *(float4*)&Klds[lr][c4] = kv;
    *(float4*)&Vlds[lr][c4] = vv;
  }
  for (int idx = tid; idx < 32 * 32; idx += 256) {
    int lr = idx >> 5, c4 = (idx & 31) * 4;
    *(float4*)&Qlds[lr][c4] = *(const float4*)(Qm + (size_t)(rowbase + lr) * 128 + c4);
  }
  __syncthreads();
  const float invscale = 0.08838834764831845f;  // 1/sqrt(128)
  // phase 1: scores, lane = t (0..63); wave owns rows wv*8..wv*8+7
#pragma unroll 1
  for (int rr = 0; rr < 8; ++rr) {
    int r = wv * 8 + rr;
    int krow = r + 64 - lane;   // LDS row of neighbor j = i+32-t
    float accs = 0.f;
#pragma unroll
    for (int d4 = 0; d4 < 128; d4 += 4) {
      float4 q = *(const float4*)&Qlds[r][d4];
      float4 k = *(const float4*)&Klds[krow][d4];
      accs += q.x * k.x + q.y * k.y + q.z * k.z + q.w * k.w;
    }
    sc[r][lane] = accs * invscale;
  }
  // t = 64 (neighbor j = i-32): 8 lanes per row, 16-d chunks + shfl reduce
  {
    int r = wv * 8 + (lane >> 3);
    int dg = lane & 7;
    float p = 0.f;
#pragma unroll
    for (int e = 0; e < 16; ++e) {
      int d = dg * 16 + e;
      p += Qlds[r][d] * Klds[r][d];
    }
    p += __shfl_xor(p, 1);
    p += __shfl_xor(p, 2);
    p += __shfl_xor(p, 4);
    if (dg == 0) sc[r][64] = p * invscale;
  }
  // softmax over 65 entries per row; write weights to d_out and LDS
#pragma unroll 1
  for (int rr = 0; rr < 8; ++rr) {
    int r = wv * 8 + rr;
    float a = sc[r][lane];
    float bb = (lane == 0) ? sc[r][64] : -1e30f;
    float mx = fmaxf(a, bb);
#pragma unroll
    for (int o = 1; o < 64; o <<= 1) mx = fmaxf(mx, __shfl_xor(mx, o));
    float ea = __expf(a - mx);
    float eb = (lane == 0) ? __expf(bb - mx) : 0.f;
    float sm = ea + eb;
#pragma unroll
    for (int o = 1; o < 64; o <<= 1) sm += __shfl_xor(sm, o);
    float inv = 1.0f / sm;
    float wa = ea * inv;
    sc[r][lane] = wa;
    size_t ob = (size_t)(rowbase + r) * 65;
    attw[ob + lane] = wa;
    if (lane == 0) {
      float wb = eb * inv;
      sc[r][64] = wb;
      attw[ob + 64] = wb;
    }
  }
  // phase 3: context (lane owns d=lane, d=lane+64) + out projection
#pragma unroll 1
  for (int rr = 0; rr < 8; ++rr) {
    int r = wv * 8 + rr;
    float c0 = 0.f, c1 = 0.f;
#pragma unroll 1
    for (int t = 0; t < 65; ++t) {
      float wt = sc[r][t];
      int vr = r + 64 - t;
      c0 = __builtin_fmaf(wt, Vlds[vr][lane], c0);
      c1 = __builtin_fmaf(wt, Vlds[vr][lane + 64], c1);
    }
    c0 *= invscale;
    c1 *= invscale;
    float2 w0 = *(const float2*)(Wo + lane * 2);
    float2 w1 = *(const float2*)(Wo + (lane + 64) * 2);
    float p0 = c0 * w0.x + c1 * w1.x;
    float p1 = c0 * w0.y + c1 * w1.y;
#pragma unroll
    for (int o = 1; o < 64; o <<= 1) {
      p0 += __shfl_xor(p0, o);
      p1 += __shfl_xor(p1, o);
    }
    if (lane == 0) {
      size_t ob = (size_t)(rowbase + r) * 2;
      outp[ob]     = p0 + bo[0];
      outp[ob + 1] = p1 + bo[1];
    }
  }
}

extern "C" void kernel_launch(void* const* d_in, const int* in_sizes, int n_in,
                              void* d_out, int out_size, void* d_ws, size_t ws_size,
                              hipStream_t stream) {
  const float* x  = (const float*)d_in[0];
  const float* W1 = (const float*)d_in[1];
  const float* b1 = (const float*)d_in[2];
  const float* Wq = (const float*)d_in[3];
  const float* Wk = (const float*)d_in[4];
  const float* Wv = (const float*)d_in[5];
  const float* Wo = (const float*)d_in[6];
  const float* bo = (const float*)d_in[7];
  float* out  = (float*)d_out;            // (4,2048,2)
  float* attw = out + 16384;              // (4,2048,65)

  ushort* W1t  = (ushort*)d_ws;           // 128x2048 bf16
  ushort* Wqkv = W1t + 262144;            // 3 x 128x128 bf16 (transposed)
  ushort* h_bf = Wqkv + 3 * 16384;        // 8192x128 bf16
  float* Q  = (float*)(h_bf + 1048576);   // 8192x128 f32
  float* Km = Q + 1048576;
  float* Vm = Km + 1048576;

  k_prep<<<1216, 256, 0, stream>>>(W1, Wq, Wk, Wv, W1t, Wqkv);
  k_gemm1<<<256, 256, 0, stream>>>(x, W1t, b1, h_bf);
  k_qkv<<<dim3(256, 3), 256, 0, stream>>>(h_bf, Wqkv, Q);
  k_attn<<<256, 256, 0, stream>>>(Q, Km, Vm, Wo, bo, out, attw);
}

// Round 2
// 98.908 us; speedup vs baseline: 1.0787x; 1.0787x over previous
//
#include <hip/hip_runtime.h>
#include <hip/hip_bf16.h>

typedef __attribute__((ext_vector_type(8))) short short8;
typedef __attribute__((ext_vector_type(4))) short short4v;
typedef __attribute__((ext_vector_type(4))) float f32x4;

#define MFMA16(a,b,c) __builtin_amdgcn_mfma_f32_16x16x32_bf16(a,b,c,0,0,0)

__device__ __forceinline__ ushort f2bf(float f) {
  union { float f; unsigned u; } v; v.f = f;
  unsigned u = v.u;
  return (ushort)((u + 0x7fffu + ((u >> 16) & 1u)) >> 16);
}

__device__ __forceinline__ float posenc(float sf, int k) {
  // inv_freq = 10000^(-(k>>1)/64); angle in revolutions for v_sin/v_cos
  float c = exp2f((float)(k >> 1) * -0.2076205059304595f) * 0.15915494309189535f;
  float p = sf * c;
  float r = __builtin_fmaf(sf, c, -rintf(p));   // exact fract via fma
  return (k & 1) ? __builtin_amdgcn_cosf(r) : __builtin_amdgcn_sinf(r);
}

// ---------------------------------------------------------------------------
// Prep: W1 (2048x128 f32) -> W1t[n][k] bf16 (coalesced LDS-tile transpose);
// Wq/Wk/Wv (128x128) -> transposed bf16 concatenated.
// Grid: 64 transpose blocks + 192 qkv blocks, 256 threads.
// ---------------------------------------------------------------------------
__global__ __launch_bounds__(256) void k_prep(const float* __restrict__ W1,
                                              const float* __restrict__ Wq,
                                              const float* __restrict__ Wk,
                                              const float* __restrict__ Wv,
                                              ushort* __restrict__ W1t,
                                              ushort* __restrict__ Wqkvt) {
  const int bid = blockIdx.x, tid = threadIdx.x;
  if (bid < 64) {
    __shared__ float Tl[64][65];
    const int kt0 = (bid >> 1) * 64, nt0 = (bid & 1) * 64;
    const int row = tid >> 2, c0 = (tid & 3) * 16;
#pragma unroll
    for (int e = 0; e < 16; e += 4) {
      float4 f = *(const float4*)(W1 + (size_t)(kt0 + row) * 128 + nt0 + c0 + e);
      Tl[row][c0 + e] = f.x; Tl[row][c0 + e + 1] = f.y;
      Tl[row][c0 + e + 2] = f.z; Tl[row][c0 + e + 3] = f.w;
    }
    __syncthreads();
    const int nrow = tid >> 2, kc0 = (tid & 3) * 16;
    ushort* wp = W1t + (size_t)(nt0 + nrow) * 2048 + kt0 + kc0;
#pragma unroll
    for (int e = 0; e < 16; ++e) wp[e] = f2bf(Tl[kc0 + e][nrow]);
  } else {
    int r = (bid - 64) * 256 + tid;
    if (r < 3 * 16384) {
      int m = r >> 14, e = r & 16383;
      int n = e >> 7, k = e & 127;
      const float* W = (m == 0) ? Wq : (m == 1) ? Wk : Wv;
      Wqkvt[r] = f2bf(W[k * 128 + n]);
    }
  }
}

// ---------------------------------------------------------------------------
// GEMM1: h = relu((x + posenc) @ W1 + b1) -> bf16.
// BM=16, BN=128. 512 threads = 2 K-groups x 4 waves; group g covers K-half.
// Grid 512 blocks -> 2 blocks/CU, 16 waves/CU.
// ---------------------------------------------------------------------------
__global__ __launch_bounds__(512) void k_gemm1(const float* __restrict__ x,
                                               const ushort* __restrict__ W1t,
                                               const float* __restrict__ b1,
                                               ushort* __restrict__ h_bf) {
  __shared__ __align__(16) char smem[41472];
  const int tid = threadIdx.x;
  const int g = tid >> 8;                 // K-group
  const int gtid = tid & 255;
  const int lane = tid & 63;
  const int wv = (tid >> 6) & 3;          // wave within group
  short (*Al)[72] = (short(*)[72])(smem + g * 2304);            // [16][72]
  short (*Bl)[72] = (short(*)[72])(smem + 4608 + g * 18432);    // [128][72]
  const int i0 = blockIdx.x * 16;
  const int arow = gtid >> 4, akc = (gtid & 15) * 4;
  const int brow = gtid >> 1, bk0 = (gtid & 1) * 32;
  const int grow = i0 + arow;
  const float sf = (float)(grow & 2047);
  const int fr = lane & 15, kg = (lane >> 4) * 8;
  f32x4 acc[2] = {};
  for (int it = 0; it < 16; ++it) {
    const int kt = g * 1024 + it * 64;
    // stage A = x + posenc -> bf16
    {
      float4 f = *(const float4*)(x + (size_t)grow * 2048 + kt + akc);
      short4v av;
      av[0] = (short)f2bf(f.x + posenc(sf, kt + akc));
      av[1] = (short)f2bf(f.y + posenc(sf, kt + akc + 1));
      av[2] = (short)f2bf(f.z + posenc(sf, kt + akc + 2));
      av[3] = (short)f2bf(f.w + posenc(sf, kt + akc + 3));
      *(short4v*)&Al[arow][akc] = av;
    }
    // stage B from W1t (bf16, n-major)
    {
      const ushort* wp = W1t + (size_t)brow * 2048 + kt + bk0;
#pragma unroll
      for (int e = 0; e < 4; ++e)
        *(short8*)&Bl[brow][bk0 + e * 8] = *(const short8*)(wp + e * 8);
    }
    __syncthreads();
#pragma unroll
    for (int kk = 0; kk < 2; ++kk) {
      short8 a   = *(const short8*)&Al[fr][kk * 32 + kg];
      short8 b0  = *(const short8*)&Bl[wv * 32 + fr][kk * 32 + kg];
      short8 b1v = *(const short8*)&Bl[wv * 32 + 16 + fr][kk * 32 + kg];
      acc[0] = MFMA16(a, b0,  acc[0]);
      acc[1] = MFMA16(a, b1v, acc[1]);
    }
    __syncthreads();
  }
  // cross-group reduce through LDS (overlays staging region; all reads done)
  float (*Cred)[128] = (float(*)[128])smem;
  if (g == 1) {
#pragma unroll
    for (int n2 = 0; n2 < 2; ++n2)
#pragma unroll
      for (int r = 0; r < 4; ++r)
        Cred[(lane >> 4) * 4 + r][wv * 32 + n2 * 16 + fr] = acc[n2][r];
  }
  __syncthreads();
  if (g == 0) {
#pragma unroll
    for (int n2 = 0; n2 < 2; ++n2) {
      const int col = wv * 32 + n2 * 16 + fr;
      const float bv = b1[col];
#pragma unroll
      for (int r = 0; r < 4; ++r) {
        const int row_l = (lane >> 4) * 4 + r;
        float v = acc[n2][r] + Cred[row_l][col] + bv;
        v = v > 0.f ? v : 0.f;
        h_bf[(size_t)(i0 + row_l) * 128 + col] = f2bf(v);
      }
    }
  }
}

// ---------------------------------------------------------------------------
// QKV: {Q,K,V} = h_bf @ {Wq,Wk,Wv}, fp32 out. BM=16, grid (512, 3).
// ---------------------------------------------------------------------------
__global__ __launch_bounds__(256) void k_qkv(const ushort* __restrict__ h_bf,
                                             const ushort* __restrict__ Wtb,
                                             float* __restrict__ outb) {
  __shared__ short Al[16][136];
  __shared__ short Bl[128][136];
  const int tid = threadIdx.x;
  const int lane = tid & 63, wv = tid >> 6;
  const int i0 = blockIdx.x * 16;
  const ushort* Wt = Wtb + (size_t)blockIdx.y * 16384;
  float* out = outb + (size_t)blockIdx.y * 1048576;
  {
    const int row = tid >> 4, c = (tid & 15) * 8;
    *(short8*)&Al[row][c] = *(const short8*)(h_bf + (size_t)(i0 + row) * 128 + c);
  }
  {
    const int n = tid >> 1, h = (tid & 1) * 64;
    const ushort* wp = Wt + (size_t)n * 128 + h;
#pragma unroll
    for (int e = 0; e < 8; ++e)
      *(short8*)&Bl[n][h + e * 8] = *(const short8*)(wp + e * 8);
  }
  __syncthreads();
  const int fr = lane & 15, kg = (lane >> 4) * 8;
  f32x4 acc[2] = {};
#pragma unroll
  for (int kk = 0; kk < 4; ++kk) {
    short8 a   = *(const short8*)&Al[fr][kk * 32 + kg];
    short8 b0  = *(const short8*)&Bl[wv * 32 + fr][kk * 32 + kg];
    short8 b1v = *(const short8*)&Bl[wv * 32 + 16 + fr][kk * 32 + kg];
    acc[0] = MFMA16(a, b0,  acc[0]);
    acc[1] = MFMA16(a, b1v, acc[1]);
  }
#pragma unroll
  for (int n2 = 0; n2 < 2; ++n2)
#pragma unroll
    for (int r = 0; r < 4; ++r) {
      const int row = i0 + (lane >> 4) * 4 + r;
      const int col = wv * 32 + n2 * 16 + fr;
      out[(size_t)row * 128 + col] = acc[n2][r];
    }
}

// ---------------------------------------------------------------------------
// Attention: K staged in LDS (XOR slot swizzle, conflict-free transposed
// reads); V read直 from L2 (row-uniform); Q staged (broadcast reads).
// 512 threads (8 waves x 4 rows), grid 256.
// ---------------------------------------------------------------------------
__global__ __launch_bounds__(512) void k_attn(const float* __restrict__ Qm,
                                              const float* __restrict__ Km,
                                              const float* __restrict__ Vm,
                                              const float* __restrict__ Wo,
                                              const float* __restrict__ bo,
                                              float* __restrict__ outp,
                                              float* __restrict__ attw) {
  __shared__ float Klds[96 * 128];    // row-swizzled: slot' = slot ^ (row&7)
  __shared__ float Qlds[32][128];
  __shared__ float sc[32][66];
  const int tid = threadIdx.x;
  const int lane = tid & 63, wv = tid >> 6;
  const int bx = blockIdx.x;
  const int b = bx >> 6;
  const int i0g = (bx & 63) << 5;
  const int rowbase = b * 2048 + i0g;
  // stage K rows j = i0g-32 .. i0g+63 (zeros outside [0,2048)), swizzled
  for (int idx = tid; idx < 96 * 32; idx += 512) {
    const int lr = idx >> 5, s = idx & 31;
    const int j = i0g - 32 + lr;
    float4 kv = {0.f, 0.f, 0.f, 0.f};
    if (j >= 0 && j < 2048)
      kv = *(const float4*)(Km + (size_t)(b * 2048 + j) * 128 + s * 4);
    *(float4*)(Klds + lr * 128 + ((s ^ (lr & 7)) << 2)) = kv;
  }
  for (int idx = tid; idx < 32 * 32; idx += 512) {
    const int lr = idx >> 5, s = idx & 31;
    *(float4*)&Qlds[lr][s * 4] =
        *(const float4*)(Qm + (size_t)(rowbase + lr) * 128 + s * 4);
  }
  __syncthreads();
  const float invscale = 0.08838834764831845f;  // 1/sqrt(128)
  // phase 1: scores. wave owns rows wv*4..wv*4+3; lane = t (0..63)
#pragma unroll 1
  for (int rr = 0; rr < 4; ++rr) {
    const int r = wv * 4 + rr;
    const int krow = r + 64 - lane;   // LDS row of neighbor j = i+32-t
    const int sw = (krow & 7);
    float accs = 0.f;
#pragma unroll
    for (int d4 = 0; d4 < 128; d4 += 4) {
      float4 q = *(const float4*)&Qlds[r][d4];
      float4 k = *(const float4*)(Klds + krow * 128 + ((((d4 >> 2) ^ sw)) << 2));
      accs += q.x * k.x + q.y * k.y + q.z * k.z + q.w * k.w;
    }
    sc[r][lane] = accs * invscale;
  }
  // t = 64 (neighbor j = i-32, LDS row r): 16 lanes per row
  {
    const int r = wv * 4 + (lane >> 4);
    const int dg = lane & 15;
    float p = 0.f;
#pragma unroll
    for (int e = 0; e < 8; ++e) {
      const int d = dg * 8 + e;
      p += Qlds[r][d] * Klds[r * 128 + (((d >> 2) ^ (r & 7)) << 2) + (d & 3)];
    }
    p += __shfl_xor(p, 1);
    p += __shfl_xor(p, 2);
    p += __shfl_xor(p, 4);
    p += __shfl_xor(p, 8);
    if (dg == 0) sc[r][64] = p * invscale;
  }
  // softmax over 65 entries per row (rows owned by this wave -> no barrier)
#pragma unroll 1
  for (int rr = 0; rr < 4; ++rr) {
    const int r = wv * 4 + rr;
    float a = sc[r][lane];
    float bb = (lane == 0) ? sc[r][64] : -1e30f;
    float mx = fmaxf(a, bb);
#pragma unroll
    for (int o = 1; o < 64; o <<= 1) mx = fmaxf(mx, __shfl_xor(mx, o));
    float ea = __expf(a - mx);
    float eb = (lane == 0) ? __expf(bb - mx) : 0.f;
    float sm = ea + eb;
#pragma unroll
    for (int o = 1; o < 64; o <<= 1) sm += __shfl_xor(sm, o);
    float inv = 1.0f / sm;
    float wa = ea * inv;
    sc[r][lane] = wa;
    size_t ob = (size_t)(rowbase + r) * 65;
    attw[ob + lane] = wa;
    if (lane == 0) {
      float wb = eb * inv;
      sc[r][64] = wb;
      attw[ob + 64] = wb;
    }
  }
  // phase 3: context from global V (row-uniform, L2-hot) + out projection.
  // lane owns d = 2*lane, 2*lane+1.
#pragma unroll 1
  for (int rr = 0; rr < 4; ++rr) {
    const int r = wv * 4 + rr;
    float c0 = 0.f, c1 = 0.f;
#pragma unroll 1
    for (int t = 0; t < 65; ++t) {
      const int j = i0g + r + 32 - t;
      if (j >= 0 && j < 2048) {
        const float wt = sc[r][t];
        float2 v2 = *(const float2*)(Vm + (size_t)(b * 2048 + j) * 128 + 2 * lane);
        c0 = __builtin_fmaf(wt, v2.x, c0);
        c1 = __builtin_fmaf(wt, v2.y, c1);
      }
    }
    c0 *= invscale;
    c1 *= invscale;
    float4 w = *(const float4*)(Wo + 4 * lane);   // rows 2l, 2l+1 of (128x2)
    float p0 = c0 * w.x + c1 * w.z;
    float p1 = c0 * w.y + c1 * w.w;
#pragma unroll
    for (int o = 1; o < 64; o <<= 1) {
      p0 += __shfl_xor(p0, o);
      p1 += __shfl_xor(p1, o);
    }
    if (lane == 0) {
      size_t ob = (size_t)(rowbase + r) * 2;
      outp[ob]     = p0 + bo[0];
      outp[ob + 1] = p1 + bo[1];
    }
  }
}

extern "C" void kernel_launch(void* const* d_in, const int* in_sizes, int n_in,
                              void* d_out, int out_size, void* d_ws, size_t ws_size,
                              hipStream_t stream) {
  const float* x  = (const float*)d_in[0];
  const float* W1 = (const float*)d_in[1];
  const float* b1 = (const float*)d_in[2];
  const float* Wq = (const float*)d_in[3];
  const float* Wk = (const float*)d_in[4];
  const float* Wv = (const float*)d_in[5];
  const float* Wo = (const float*)d_in[6];
  const float* bo = (const float*)d_in[7];
  float* out  = (float*)d_out;            // (4,2048,2)
  float* attw = out + 16384;              // (4,2048,65)

  ushort* W1t  = (ushort*)d_ws;           // 128x2048 bf16
  ushort* Wqkv = W1t + 262144;            // 3 x 128x128 bf16 (transposed)
  ushort* h_bf = Wqkv + 3 * 16384;        // 8192x128 bf16
  float* Q  = (float*)(h_bf + 1048576);   // 8192x128 f32
  float* Km = Q + 1048576;
  float* Vm = Km + 1048576;

  k_prep<<<256, 256, 0, stream>>>(W1, Wq, Wk, Wv, W1t, Wqkv);
  k_gemm1<<<512, 512, 0, stream>>>(x, W1t, b1, h_bf);
  k_qkv<<<dim3(512, 3), 256, 0, stream>>>(h_bf, Wqkv, Q);
  k_attn<<<256, 512, 0, stream>>>(Q, Km, Vm, Wo, bo, out, attw);
}

// Round 3
// 49.968 us; speedup vs baseline: 2.1352x; 1.9794x over previous
//
#include <hip/hip_runtime.h>
#include <hip/hip_bf16.h>

typedef __attribute__((ext_vector_type(8))) _Float16 half8;
typedef __attribute__((ext_vector_type(4))) _Float16 half4;
typedef __attribute__((ext_vector_type(4))) float f32x4;

#define MFMAH(a,b,c) __builtin_amdgcn_mfma_f32_16x16x32_f16(a,b,c,0,0,0)

__device__ __forceinline__ float posenc(float sf, int k) {
  // inv_freq = 10000^(-(k>>1)/64); angle in revolutions for v_sin/v_cos
  float c = exp2f((float)(k >> 1) * -0.2076205059304595f) * 0.15915494309189535f;
  float p = sf * c;
  float r = __builtin_fmaf(sf, c, -rintf(p));   // exact fract via fma
  return (k & 1) ? __builtin_amdgcn_cosf(r) : __builtin_amdgcn_sinf(r);
}

// ---------------------------------------------------------------------------
// Prep: W1 (2048x128 f32) -> W1t[n][k] f16 (coalesced LDS-tile transpose);
// Wq/Wk/Wv (128x128) -> transposed f16 concatenated.
// ---------------------------------------------------------------------------
__global__ __launch_bounds__(256) void k_prep(const float* __restrict__ W1,
                                              const float* __restrict__ Wq,
                                              const float* __restrict__ Wk,
                                              const float* __restrict__ Wv,
                                              _Float16* __restrict__ W1t,
                                              _Float16* __restrict__ Wqkvt) {
  const int bid = blockIdx.x, tid = threadIdx.x;
  if (bid < 64) {
    __shared__ float Tl[64][65];
    const int kt0 = (bid >> 1) * 64, nt0 = (bid & 1) * 64;
    const int row = tid >> 2, c0 = (tid & 3) * 16;
#pragma unroll
    for (int e = 0; e < 16; e += 4) {
      float4 f = *(const float4*)(W1 + (size_t)(kt0 + row) * 128 + nt0 + c0 + e);
      Tl[row][c0 + e] = f.x; Tl[row][c0 + e + 1] = f.y;
      Tl[row][c0 + e + 2] = f.z; Tl[row][c0 + e + 3] = f.w;
    }
    __syncthreads();
    const int nrow = tid >> 2, kc0 = (tid & 3) * 16;
    _Float16* wp = W1t + (size_t)(nt0 + nrow) * 2048 + kt0 + kc0;
#pragma unroll
    for (int e = 0; e < 16; ++e) wp[e] = (_Float16)Tl[kc0 + e][nrow];
  } else {
    int r = (bid - 64) * 256 + tid;
    if (r < 3 * 16384) {
      int m = r >> 14, e = r & 16383;
      int n = e >> 7, k = e & 127;
      const float* W = (m == 0) ? Wq : (m == 1) ? Wk : Wv;
      Wqkvt[r] = (_Float16)W[k * 128 + n];
    }
  }
}

// ---------------------------------------------------------------------------
// GEMM1: h = relu((x + posenc) @ W1 + b1) -> f16.
// BM=16, BN=128. 512 threads = 2 K-groups x 4 waves. Grid 512.
// ---------------------------------------------------------------------------
__global__ __launch_bounds__(512) void k_gemm1(const float* __restrict__ x,
                                               const _Float16* __restrict__ W1t,
                                               const float* __restrict__ b1,
                                               _Float16* __restrict__ hbuf) {
  __shared__ __align__(16) char smem[41472];
  const int tid = threadIdx.x;
  const int g = tid >> 8;                 // K-group
  const int gtid = tid & 255;
  const int lane = tid & 63;
  const int wv = (tid >> 6) & 3;          // wave within group
  _Float16 (*Al)[72] = (_Float16(*)[72])(smem + g * 2304);            // [16][72]
  _Float16 (*Bl)[72] = (_Float16(*)[72])(smem + 4608 + g * 18432);    // [128][72]
  const int i0 = blockIdx.x * 16;
  const int arow = gtid >> 4, akc = (gtid & 15) * 4;
  const int brow = gtid >> 1, bk0 = (gtid & 1) * 32;
  const int grow = i0 + arow;
  const float sf = (float)(grow & 2047);
  const int fr = lane & 15, kg = (lane >> 4) * 8;
  f32x4 acc[2] = {};
  for (int it = 0; it < 16; ++it) {
    const int kt = g * 1024 + it * 64;
    // stage A = x + posenc -> f16
    {
      float4 f = *(const float4*)(x + (size_t)grow * 2048 + kt + akc);
      half4 av;
      av[0] = (_Float16)(f.x + posenc(sf, kt + akc));
      av[1] = (_Float16)(f.y + posenc(sf, kt + akc + 1));
      av[2] = (_Float16)(f.z + posenc(sf, kt + akc + 2));
      av[3] = (_Float16)(f.w + posenc(sf, kt + akc + 3));
      *(half4*)&Al[arow][akc] = av;
    }
    // stage B from W1t (f16, n-major)
    {
      const _Float16* wp = W1t + (size_t)brow * 2048 + kt + bk0;
#pragma unroll
      for (int e = 0; e < 4; ++e)
        *(half8*)&Bl[brow][bk0 + e * 8] = *(const half8*)(wp + e * 8);
    }
    __syncthreads();
#pragma unroll
    for (int kk = 0; kk < 2; ++kk) {
      half8 a   = *(const half8*)&Al[fr][kk * 32 + kg];
      half8 b0  = *(const half8*)&Bl[wv * 32 + fr][kk * 32 + kg];
      half8 b1v = *(const half8*)&Bl[wv * 32 + 16 + fr][kk * 32 + kg];
      acc[0] = MFMAH(a, b0,  acc[0]);
      acc[1] = MFMAH(a, b1v, acc[1]);
    }
    __syncthreads();
  }
  // cross-group reduce through LDS (overlays staging region; all reads done)
  float (*Cred)[128] = (float(*)[128])smem;
  if (g == 1) {
#pragma unroll
    for (int n2 = 0; n2 < 2; ++n2)
#pragma unroll
      for (int r = 0; r < 4; ++r)
        Cred[(lane >> 4) * 4 + r][wv * 32 + n2 * 16 + fr] = acc[n2][r];
  }
  __syncthreads();
  if (g == 0) {
#pragma unroll
    for (int n2 = 0; n2 < 2; ++n2) {
      const int col = wv * 32 + n2 * 16 + fr;
      const float bv = b1[col];
#pragma unroll
      for (int r = 0; r < 4; ++r) {
        const int row_l = (lane >> 4) * 4 + r;
        float v = acc[n2][r] + Cred[row_l][col] + bv;
        v = v > 0.f ? v : 0.f;
        hbuf[(size_t)(i0 + row_l) * 128 + col] = (_Float16)v;
      }
    }
  }
}

// ---------------------------------------------------------------------------
// QKV: {Q,K,V} = h @ {Wq,Wk,Wv}, f16 out. BM=16, grid (512, 3).
// ---------------------------------------------------------------------------
__global__ __launch_bounds__(256) void k_qkv(const _Float16* __restrict__ hbuf,
                                             const _Float16* __restrict__ Wtb,
                                             _Float16* __restrict__ outb) {
  __shared__ _Float16 Al[16][136];
  __shared__ _Float16 Bl[128][136];
  const int tid = threadIdx.x;
  const int lane = tid & 63, wv = tid >> 6;
  const int i0 = blockIdx.x * 16;
  const _Float16* Wt = Wtb + (size_t)blockIdx.y * 16384;
  _Float16* out = outb + (size_t)blockIdx.y * 1048576;
  {
    const int row = tid >> 4, c = (tid & 15) * 8;
    *(half8*)&Al[row][c] = *(const half8*)(hbuf + (size_t)(i0 + row) * 128 + c);
  }
  {
    const int n = tid >> 1, h0 = (tid & 1) * 64;
    const _Float16* wp = Wt + (size_t)n * 128 + h0;
#pragma unroll
    for (int e = 0; e < 8; ++e)
      *(half8*)&Bl[n][h0 + e * 8] = *(const half8*)(wp + e * 8);
  }
  __syncthreads();
  const int fr = lane & 15, kg = (lane >> 4) * 8;
  f32x4 acc[2] = {};
#pragma unroll
  for (int kk = 0; kk < 4; ++kk) {
    half8 a   = *(const half8*)&Al[fr][kk * 32 + kg];
    half8 b0  = *(const half8*)&Bl[wv * 32 + fr][kk * 32 + kg];
    half8 b1v = *(const half8*)&Bl[wv * 32 + 16 + fr][kk * 32 + kg];
    acc[0] = MFMAH(a, b0,  acc[0]);
    acc[1] = MFMAH(a, b1v, acc[1]);
  }
#pragma unroll
  for (int n2 = 0; n2 < 2; ++n2)
#pragma unroll
    for (int r = 0; r < 4; ++r) {
      const int row = i0 + (lane >> 4) * 4 + r;
      const int col = wv * 32 + n2 * 16 + fr;
      out[(size_t)row * 128 + col] = (_Float16)acc[n2][r];
    }
}

// ---------------------------------------------------------------------------
// Attention via MFMA. Block = 16 q-rows of one batch; 4 waves; grid 512.
// K-window: lr in [0,80) <-> j = i0-32+lr (zero rows outside sequence ->
// score 0, INCLUDED in softmax, matching reference zero-padding).
// Band mask: q-row r keeps cols lr in [r, r+64] (65 entries).
// ---------------------------------------------------------------------------
__global__ __launch_bounds__(256) void k_attn(const _Float16* __restrict__ Qg,
                                              const _Float16* __restrict__ Kg,
                                              const _Float16* __restrict__ Vg,
                                              const float* __restrict__ Wo,
                                              const float* __restrict__ bo,
                                              float* __restrict__ outp,
                                              float* __restrict__ attwg) {
  __shared__ _Float16 Qs[16][136];
  __shared__ _Float16 Ks[80][136];
  __shared__ _Float16 Vs[96][136];
  __shared__ _Float16 Ps[16][104];
  __shared__ float sc[16][84];
  __shared__ float aw[16 * 65];
  __shared__ float wol[128][2];
  __shared__ float proj[4][16][2];
  const int tid = threadIdx.x;
  const int lane = tid & 63, wv = tid >> 6;
  const int b = blockIdx.x >> 7;
  const int i0 = (blockIdx.x & 127) << 4;
  const int rowbase = b * 2048 + i0;
  const float invscale = 0.08838834764831845f;  // 1/sqrt(128)

  // ---- stage Q (16 rows), K (80 rows), V (96 rows: 80 real + 16 zero) ----
  {
    const int row = tid >> 4, d8 = (tid & 15) * 8;
    *(half8*)&Qs[row][d8] = *(const half8*)(Qg + (size_t)(rowbase + row) * 128 + d8);
  }
#pragma unroll
  for (int it = 0; it < 5; ++it) {
    const int idx = it * 256 + tid;
    const int lr = idx >> 4, d8 = (idx & 15) * 8;
    const int j = i0 - 32 + lr;
    half8 kv = {0, 0, 0, 0, 0, 0, 0, 0};
    if (j >= 0 && j < 2048)
      kv = *(const half8*)(Kg + (size_t)(b * 2048 + j) * 128 + d8);
    *(half8*)&Ks[lr][d8] = kv;
  }
#pragma unroll
  for (int it = 0; it < 6; ++it) {
    const int idx = it * 256 + tid;
    const int lr = idx >> 4, d8 = (idx & 15) * 8;
    const int j = i0 - 32 + lr;
    half8 vv = {0, 0, 0, 0, 0, 0, 0, 0};
    if (lr < 80 && j >= 0 && j < 2048)
      vv = *(const half8*)(Vg + (size_t)(b * 2048 + j) * 128 + d8);
    *(half8*)&Vs[lr][d8] = vv;
  }
  wol[tid >> 1][tid & 1] = Wo[tid];
  __syncthreads();

  const int fr = lane & 15, kg8 = (lane >> 4) * 8;
  // ---- QK^T: C[16 q][80 k] = 5 col-tiles; wave wv -> ct=wv, wave0 also ct=4
  {
    const int nct = (wv == 0) ? 2 : 1;
    for (int p = 0; p < nct; ++p) {
      const int ct = (p == 0) ? wv : 4;
      f32x4 acc = {};
#pragma unroll
      for (int kk = 0; kk < 4; ++kk) {
        half8 a  = *(const half8*)&Qs[fr][kk * 32 + kg8];
        half8 bb = *(const half8*)&Ks[ct * 16 + fr][kk * 32 + kg8];
        acc = MFMAH(a, bb, acc);
      }
#pragma unroll
      for (int r = 0; r < 4; ++r)
        sc[(lane >> 4) * 4 + r][ct * 16 + fr] = acc[r] * invscale;
    }
  }
  __syncthreads();

  // ---- banded softmax; wave wv owns q-rows 4wv..4wv+3 ----
#pragma unroll 1
  for (int rr = 0; rr < 4; ++rr) {
    const int r = wv * 4 + rr;
    const int c0 = lane;
    const bool ib0 = (c0 >= r);               // c0 <= 63 <= r+64 always
    const bool ib1 = (lane <= r);             // col 64+lane <= r+64
    float a0 = ib0 ? sc[r][c0] : -1e30f;
    float a1 = ib1 ? sc[r][64 + lane] : -1e30f;
    float mx = fmaxf(a0, a1);
#pragma unroll
    for (int o = 1; o < 64; o <<= 1) mx = fmaxf(mx, __shfl_xor(mx, o));
    float e0 = ib0 ? __expf(a0 - mx) : 0.f;
    float e1 = ib1 ? __expf(a1 - mx) : 0.f;
    float sm = e0 + e1;
#pragma unroll
    for (int o = 1; o < 64; o <<= 1) sm += __shfl_xor(sm, o);
    const float inv = 1.0f / sm;
    const float w0 = e0 * inv, w1 = e1 * inv;
    if (ib0) aw[r * 65 + (r + 64 - c0)] = w0;   // t = r+64-c in [1..64]
    if (ib1) aw[r * 65 + (r - lane)] = w1;      // t = r-lane in [0..r]
    Ps[r][c0] = (_Float16)w0;
    if (lane < 32) Ps[r][64 + lane] = (_Float16)((lane < 16) ? w1 : 0.f);
  }
  __syncthreads();

  // ---- attw copy-out (contiguous 1040 floats per block) ----
  for (int i = tid; i < 1040; i += 256)
    attwg[(size_t)rowbase * 65 + i] = aw[i];

  // ---- PV: C2[16 q][128 d] = P(16x96) @ V(96x128); wave wv -> d-tiles 2wv,2wv+1
  f32x4 c2[2] = {};
#pragma unroll
  for (int kk = 0; kk < 3; ++kk) {
    half8 a = *(const half8*)&Ps[fr][kk * 32 + kg8];
#pragma unroll
    for (int dt2 = 0; dt2 < 2; ++dt2) {
      const int d = (2 * wv + dt2) * 16 + fr;
      half8 bb;
#pragma unroll
      for (int e = 0; e < 8; ++e) bb[e] = Vs[kk * 32 + kg8 + e][d];
      c2[dt2] = MFMAH(a, bb, c2[dt2]);
    }
  }
  // ---- projection: out[q][o] = invscale * sum_d C2[q][d]*Wo[d][o] + bo[o]
#pragma unroll
  for (int r = 0; r < 4; ++r) {
    float p0 = 0.f, p1 = 0.f;
#pragma unroll
    for (int dt2 = 0; dt2 < 2; ++dt2) {
      const int d = (2 * wv + dt2) * 16 + fr;
      p0 += c2[dt2][r] * wol[d][0];
      p1 += c2[dt2][r] * wol[d][1];
    }
    p0 += __shfl_xor(p0, 1); p0 += __shfl_xor(p0, 2);
    p0 += __shfl_xor(p0, 4); p0 += __shfl_xor(p0, 8);
    p1 += __shfl_xor(p1, 1); p1 += __shfl_xor(p1, 2);
    p1 += __shfl_xor(p1, 4); p1 += __shfl_xor(p1, 8);
    if (fr == 0) {
      const int q = (lane >> 4) * 4 + r;
      proj[wv][q][0] = p0;
      proj[wv][q][1] = p1;
    }
  }
  __syncthreads();
  if (tid < 16) {
    float s0 = proj[0][tid][0] + proj[1][tid][0] + proj[2][tid][0] + proj[3][tid][0];
    float s1 = proj[0][tid][1] + proj[1][tid][1] + proj[2][tid][1] + proj[3][tid][1];
    outp[((size_t)rowbase + tid) * 2 + 0] = s0 * invscale + bo[0];
    outp[((size_t)rowbase + tid) * 2 + 1] = s1 * invscale + bo[1];
  }
}

extern "C" void kernel_launch(void* const* d_in, const int* in_sizes, int n_in,
                              void* d_out, int out_size, void* d_ws, size_t ws_size,
                              hipStream_t stream) {
  const float* x  = (const float*)d_in[0];
  const float* W1 = (const float*)d_in[1];
  const float* b1 = (const float*)d_in[2];
  const float* Wq = (const float*)d_in[3];
  const float* Wk = (const float*)d_in[4];
  const float* Wv = (const float*)d_in[5];
  const float* Wo = (const float*)d_in[6];
  const float* bo = (const float*)d_in[7];
  float* out  = (float*)d_out;            // (4,2048,2)
  float* attw = out + 16384;              // (4,2048,65)

  _Float16* W1t  = (_Float16*)d_ws;       // 128x2048
  _Float16* Wqkv = W1t + 262144;          // 3 x 128x128
  _Float16* hbuf = Wqkv + 49152;          // 8192x128
  _Float16* Qg   = hbuf + 1048576;        // 8192x128
  _Float16* Kg   = Qg + 1048576;
  _Float16* Vg   = Kg + 1048576;

  k_prep<<<256, 256, 0, stream>>>(W1, Wq, Wk, Wv, W1t, Wqkv);
  k_gemm1<<<512, 512, 0, stream>>>(x, W1t, b1, hbuf);
  k_qkv<<<dim3(512, 3), 256, 0, stream>>>(hbuf, Wqkv, Qg);
  k_attn<<<512, 256, 0, stream>>>(Qg, Kg, Vg, Wo, bo, out, attw);
}